// Round 12
// baseline (51.961 us; speedup 1.0000x reference)
//
#include <hip/hip_runtime.h>
#include <math.h>
#include <limits.h>

#define NN 8192
#define DD 128
#define BM 256        // rows per block (8 waves x 32)
#define BN 64         // cols per j-tile
#define NPART 16      // grid = 32*16 = 512 blocks (2 blocks/CU, single batch)
#define JRANGE (NN / NPART)    // 512
#define NTILES (JRANGE / BN)   // 8

typedef __attribute__((ext_vector_type(4))) int i32x4;

// ws byte offsets
#define WS_PARTIAL 0                        // 4 KB (1024 floats)
#define WS_SCALE   4096                     // 64 B
#define WS_MD      8192                     // 64 KB (8192 int2)
#define WS_HPK     (8192 + 65536)           // 32 KB
#define WS_HNK     (WS_HPK + 32768)         // 32 KB
#define WS_AH      (WS_HNK + 32768)         // 1 MB (fragment-contiguous)
#define WS_AL      (WS_AH + NN * DD)        // 1 MB

// pass 1: per-block absmax partials
__global__ __launch_bounds__(256)
void prep_k(const float* __restrict__ emb, float* __restrict__ partial) {
    int i = blockIdx.x * 256 + threadIdx.x;          // float4 index
    float4 v = reinterpret_cast<const float4*>(emb)[i];
    float m = fmaxf(fmaxf(fabsf(v.x), fabsf(v.y)), fmaxf(fabsf(v.z), fabsf(v.w)));
#pragma unroll
    for (int off = 1; off < 64; off <<= 1) m = fmaxf(m, __shfl_xor(m, off, 64));
    __shared__ float sm[4];
    if ((threadIdx.x & 63) == 0) sm[threadIdx.x >> 6] = m;
    __syncthreads();
    if (threadIdx.x == 0)
        partial[blockIdx.x] = fmaxf(fmaxf(sm[0], sm[1]), fmaxf(sm[2], sm[3]));
}

// pass 2: global amax reduce + i8 hi/lo quantize (fragment-contiguous) +
//         int metadata + key init
// int_index(row, k) = (row>>4)*512 + (k>>4)*256 + ((k>>2)&3)*64 + (row&15)*4 + (k&3)
__global__ __launch_bounds__(256)
void quantize_k(const float* __restrict__ emb, const int* __restrict__ lab,
                const float* __restrict__ partial, int* __restrict__ aH,
                int* __restrict__ aL, int2* __restrict__ md,
                int* __restrict__ hpK, int* __restrict__ hnK,
                float* __restrict__ scale) {
    __shared__ float sm[4];
    float m = fmaxf(fmaxf(partial[threadIdx.x], partial[threadIdx.x + 256]),
                    fmaxf(partial[threadIdx.x + 512], partial[threadIdx.x + 768]));
#pragma unroll
    for (int off = 1; off < 64; off <<= 1) m = fmaxf(m, __shfl_xor(m, off, 64));
    if ((threadIdx.x & 63) == 0) sm[threadIdx.x >> 6] = m;
    __syncthreads();
    float amax = fmaxf(fmaxf(fmaxf(sm[0], sm[1]), fmaxf(sm[2], sm[3])), 1e-30f);
    float sA  = amax * (1.0f / 127.0f);
    float inv = 127.0f / amax;
    float mm  = sA * sA * (1.0f / 128.0f);   // d2_true = mm * d2_int

    const int lane = threadIdx.x & 63;
    const int w    = threadIdx.x >> 6;
    const int half = lane >> 5;
    const int l32  = lane & 31;
    const int row  = blockIdx.x * 8 + w * 2 + half;

    float4 v = reinterpret_cast<const float4*>(emb)[row * 32 + l32];
    float s = 0.f;
    s = fmaf(v.x, v.x, s); s = fmaf(v.y, v.y, s);
    s = fmaf(v.z, v.z, s); s = fmaf(v.w, v.w, s);
#pragma unroll
    for (int off = 1; off < 32; off <<= 1) s += __shfl_xor(s, off, 64);

    int h = 0, l = 0;
#define QSTEP(X, K) { \
        float a = rintf((X) * inv); \
        a = fminf(fmaxf(a, -127.f), 127.f); \
        float r_ = fmaf(-a, sA, (X)); \
        float b = rintf(r_ * inv * 256.0f); \
        b = fminf(fmaxf(b, -127.f), 127.f); \
        h |= ((int)a & 255) << (8 * (K)); \
        l |= ((int)b & 255) << (8 * (K)); }
    QSTEP(v.x, 0) QSTEP(v.y, 1) QSTEP(v.z, 2) QSTEP(v.w, 3)
#undef QSTEP
    // fragment-contiguous scatter (k_int = l32)
    const int nidx = (row >> 4) * 512 + (l32 >> 4) * 256 + ((l32 >> 2) & 3) * 64
                   + (row & 15) * 4 + (l32 & 3);
    aH[nidx] = h;
    aL[nidx] = l;
    if (l32 == 0) md[row] = make_int2((int)rintf(s / mm), lab[row]);
    if (threadIdx.x < 8) {
        int r0 = blockIdx.x * 8 + threadIdx.x;
        hpK[r0] = INT_MIN;
        hnK[r0] = INT_MAX;
    }
    if (blockIdx.x == 0 && threadIdx.x == 0) scale[0] = mm;
}

__global__ __launch_bounds__(512, 4)
void hardest_k(const int* __restrict__ aH, const int* __restrict__ aL,
               const int2* __restrict__ md,
               int* __restrict__ hpK, int* __restrict__ hnK) {
    const int tid  = threadIdx.x;
    const int w    = tid >> 6;          // wave 0..7
    const int lane = tid & 63;
    const int lrow = lane & 15;
    const int lk   = lane >> 4;
    const int ib   = (int)blockIdx.x >> 4;    // 0..31
    const int part = (int)blockIdx.x & 15;    // 0..15
    const int i0   = ib * BM;
    const int jbeg = part * JRANGE;

    // persistent A fragments: 2 strips of 16 rows, K=128 in 2 chunks, hi+lo (32 regs)
    i32x4 ah[2][2], al[2][2];
#pragma unroll
    for (int s = 0; s < 2; ++s) {
        const int gA = ib * 16 + w * 2 + s;
#pragma unroll
        for (int q = 0; q < 2; ++q) {
            ah[s][q] = *reinterpret_cast<const i32x4*>(&aH[gA * 512 + q * 256 + lane * 4]);
            al[s][q] = *reinterpret_cast<const i32x4*>(&aL[gA * 512 + q * 256 + lane * 4]);
        }
    }
    int li[2][4], hp[2][4], hn[2][4];
#pragma unroll
    for (int s = 0; s < 2; ++s)
#pragma unroll
        for (int t = 0; t < 4; ++t) {
            li[s][t] = md[i0 + w * 32 + s * 16 + lk * 4 + t].y;
            hp[s][t] = INT_MIN;
            hn[s][t] = INT_MAX;
        }

#pragma unroll 1
    for (int jt = 0; jt < NTILES; ++jt) {
        const int j0 = jbeg + jt * BN;
#pragma unroll
        for (int c = 0; c < 4; ++c) {
            const int gB = (j0 >> 4) + c;
            const int bb = gB * 512 + lane * 4;
            i32x4 bh0 = *reinterpret_cast<const i32x4*>(&aH[bb]);
            i32x4 bh1 = *reinterpret_cast<const i32x4*>(&aH[bb + 256]);
            i32x4 bl0 = *reinterpret_cast<const i32x4*>(&aL[bb]);
            i32x4 bl1 = *reinterpret_cast<const i32x4*>(&aL[bb + 256]);
            int2 mj = md[j0 + c * 16 + lrow];
            i32x4 accA[2], accB[2];
            i32x4 zero = {0, 0, 0, 0};
#pragma unroll
            for (int s = 0; s < 2; ++s) { accA[s] = zero; accB[s] = zero; }
#pragma unroll
            for (int s = 0; s < 2; ++s) {
                accA[s] = __builtin_amdgcn_mfma_i32_16x16x64_i8(ah[s][0], bh0, accA[s], 0, 0, 0);
                accA[s] = __builtin_amdgcn_mfma_i32_16x16x64_i8(ah[s][1], bh1, accA[s], 0, 0, 0);
                accB[s] = __builtin_amdgcn_mfma_i32_16x16x64_i8(ah[s][0], bl0, accB[s], 0, 0, 0);
                accB[s] = __builtin_amdgcn_mfma_i32_16x16x64_i8(ah[s][1], bl1, accB[s], 0, 0, 0);
                accB[s] = __builtin_amdgcn_mfma_i32_16x16x64_i8(al[s][0], bh0, accB[s], 0, 0, 0);
                accB[s] = __builtin_amdgcn_mfma_i32_16x16x64_i8(al[s][1], bh1, accB[s], 0, 0, 0);
            }
            const int qs = mj.x, lj = mj.y;
#pragma unroll
            for (int s = 0; s < 2; ++s)
#pragma unroll
                for (int t = 0; t < 4; ++t) {
                    int e = (accA[s][t] << 8) + accB[s][t];   // exact, |e| < 2^30
                    int g = qs - e;                           // (sqj - 2*dot)/mm, exact
                    bool same = (li[s][t] == lj);
                    hp[s][t] = max(hp[s][t], same ? g : INT_MIN);
                    hn[s][t] = min(hn[s][t], same ? INT_MAX : g);
                }
        }
    }
    // reduce over the 16 column-lanes sharing each output row (int domain)
#pragma unroll
    for (int off = 1; off < 16; off <<= 1)
#pragma unroll
        for (int s = 0; s < 2; ++s)
#pragma unroll
            for (int t = 0; t < 4; ++t) {
                hp[s][t] = max(hp[s][t], __shfl_xor(hp[s][t], off, 64));
                hn[s][t] = min(hn[s][t], __shfl_xor(hn[s][t], off, 64));
            }
    if (lrow == 0) {
#pragma unroll
        for (int s = 0; s < 2; ++s)
#pragma unroll
            for (int t = 0; t < 4; ++t) {
                int i = i0 + w * 32 + s * 16 + lk * 4 + t;
                atomicMax(&hpK[i], hp[s][t]);   // order-independent => deterministic
                atomicMin(&hnK[i], hn[s][t]);
            }
    }
}

__global__ __launch_bounds__(1024)
void final_k(const int* __restrict__ hpK, const int* __restrict__ hnK,
             const int2* __restrict__ md, const float* __restrict__ scale,
             float* __restrict__ out) {
    const float mm = scale[0];
    float total = 0.f, cnt = 0.f;
    for (int i = threadIdx.x; i < NN; i += 1024) {
        int hpi = hpK[i];
        float sqi = mm * (float)md[i].x;
        float hp2 = fmaf(mm, (float)hpi, sqi);      // d^2 = sq_i + mm*g
        float hn2 = fmaf(mm, (float)hnK[i], sqi);   // INT_MAX sentinel -> huge -> excluded
        float hpd = sqrtf(fmaxf(hp2, 0.f));
        float hnd = sqrtf(fmaxf(hn2, 0.f));
        float tl = hpd - hnd + 1.0f;
        if (tl > 0.f && hpi != INT_MIN) { total += tl; cnt += 1.f; }
    }
#pragma unroll
    for (int off = 1; off < 64; off <<= 1) {
        total += __shfl_xor(total, off, 64);
        cnt   += __shfl_xor(cnt,   off, 64);
    }
    __shared__ float sT[16], sC[16];
    int wave = threadIdx.x >> 6;
    if ((threadIdx.x & 63) == 0) { sT[wave] = total; sC[wave] = cnt; }
    __syncthreads();
    if (threadIdx.x == 0) {
        float T = 0.f, Cn = 0.f;
#pragma unroll
        for (int k = 0; k < 16; ++k) { T += sT[k]; Cn += sC[k]; }
        out[0] = (Cn > 0.f) ? T / Cn : 0.f;
    }
}

extern "C" void kernel_launch(void* const* d_in, const int* in_sizes, int n_in,
                              void* d_out, int out_size, void* d_ws, size_t ws_size,
                              hipStream_t stream) {
    const float* emb = (const float*)d_in[0];
    const int*   lab = (const int*)d_in[1];
    char* ws = (char*)d_ws;
    float* partial = (float*)(ws + WS_PARTIAL);
    float* scale   = (float*)(ws + WS_SCALE);
    int2*  md      = (int2*)(ws + WS_MD);
    int*   hpK     = (int*)(ws + WS_HPK);
    int*   hnK     = (int*)(ws + WS_HNK);
    int*   aH      = (int*)(ws + WS_AH);
    int*   aL      = (int*)(ws + WS_AL);

    prep_k<<<dim3(1024), dim3(256), 0, stream>>>(emb, partial);
    quantize_k<<<dim3(NN / 8), dim3(256), 0, stream>>>(emb, lab, partial, aH, aL, md, hpK, hnK, scale);
    hardest_k<<<dim3((NN / BM) * NPART), dim3(512), 0, stream>>>(aH, aL, md, hpK, hnK);
    final_k<<<dim3(1), dim3(1024), 0, stream>>>(hpK, hnK, md, scale, (float*)d_out);
}